// Round 9
// baseline (1698.768 us; speedup 1.0000x reference)
//
#include <hip/hip_runtime.h>
#include <hip/hip_bf16.h>

#define NN 100000
#define F 128
#define C_OUT 14
#define ZP 16
#define WIN 128
#define NWIN ((NN + WIN - 1) / WIN)    // 782 windows of 128 nodes
#define WCAP 2560                      // per-window entry capacity (mean 2046, +11 sigma)
#define EBATCH 4096
#define ACCS 132                       // padded acc stride (floats) -> bank spread

typedef __attribute__((ext_vector_type(8))) short v8s;   // 8 bf16 (4 VGPRs)
typedef __attribute__((ext_vector_type(4))) float v4f;   // 4 fp32 acc

// ---------------- bf16 helpers ----------------------------------------------
static __device__ __forceinline__ unsigned short f2bf(float f) {
    unsigned int u = __float_as_uint(f);
    unsigned int r = (u + 0x7fffu + ((u >> 16) & 1u)) >> 16;   // RTN-even
    return (unsigned short)r;
}
static __device__ __forceinline__ unsigned int pack2(float a, float b) {
    return (unsigned int)f2bf(a) | ((unsigned int)f2bf(b) << 16);
}
static __device__ __forceinline__ void unpack2(unsigned int u, float& lo, float& hi) {
    lo = __uint_as_float(u << 16);
    hi = __uint_as_float(u & 0xffff0000u);
}
static __device__ __forceinline__ void atomic_acc8(float* a, uint4 u) {
    float f0, f1;
    unpack2(u.x, f0, f1); atomicAdd(a + 0, f0); atomicAdd(a + 1, f1);
    unpack2(u.y, f0, f1); atomicAdd(a + 2, f0); atomicAdd(a + 3, f1);
    unpack2(u.z, f0, f1); atomicAdd(a + 4, f0); atomicAdd(a + 5, f1);
    unpack2(u.w, f0, f1); atomicAdd(a + 6, f0); atomicAdd(a + 7, f1);
}

// ---------------------------------------------------------------------------
// bin: single pass over edges -> 782 window buckets of 4B entries
// (ent = dloc<<17 | src). Per-block LDS counts, ONE global cursor claim per
// (block, window), then writes land in a contiguous claimed range (no ranks,
// no scan, no per-edge cursor atomics). Replaces the whole CSR build.
// ---------------------------------------------------------------------------
__global__ __launch_bounds__(256) void bin_kernel(
    const int* __restrict__ src, const int* __restrict__ dst,
    unsigned* __restrict__ bucket, int* __restrict__ wcur, int E)
{
    __shared__ int cnt_s[NWIN];
    __shared__ int gbase_s[NWIN];
    const int t = threadIdx.x;
    for (int w = t; w < NWIN; w += 256) cnt_s[w] = 0;
    __syncthreads();

    int      wreg[16];
    unsigned ereg[16];
    const int e0 = blockIdx.x * EBATCH;
    #pragma unroll
    for (int j = 0; j < 16; ++j) {
        const int e = e0 + j * 256 + t;
        int w = -1; unsigned ent = 0;
        if (e < E) {
            const int d = dst[e];
            const int s = src[e];
            w   = d >> 7;
            ent = ((unsigned)(d & (WIN - 1)) << 17) | (unsigned)s;
            atomicAdd(&cnt_s[w], 1);
        }
        wreg[j] = w; ereg[j] = ent;
    }
    __syncthreads();
    for (int w = t; w < NWIN; w += 256) {
        const int c = cnt_s[w];
        gbase_s[w] = c ? atomicAdd(&wcur[w], c) : 0;
    }
    __syncthreads();
    for (int w = t; w < NWIN; w += 256) cnt_s[w] = 0;   // reuse as local cursor
    __syncthreads();
    #pragma unroll
    for (int j = 0; j < 16; ++j) {
        const int w = wreg[j];
        if (w >= 0) {
            const int pos = gbase_s[w] + atomicAdd(&cnt_s[w], 1);
            if (pos < WCAP) bucket[(size_t)w * WCAP + pos] = ereg[j];
        }
    }
}

// ---------------------------------------------------------------------------
// wprep: Wb[n][k] = bf16 of [W1l | W1r] transposed.
// ---------------------------------------------------------------------------
__global__ __launch_bounds__(256) void wprep_kernel(
    const float* __restrict__ W1l, const float* __restrict__ W1r,
    unsigned short* __restrict__ Wb)
{
    const int idx = blockIdx.x * 256 + threadIdx.x;
    if (idx >= 2 * 128 * 128) return;
    const int c   = idx >> 14;
    const int rem = idx & 16383;
    const int n   = rem >> 7;
    const int k   = rem & 127;
    const float* W = c ? W1r : W1l;
    Wb[idx] = f2bf(W[k * 128 + n]);
}

// ---------------------------------------------------------------------------
// pre1 (MFMA): pq = [ x@W1l | x@W1r + b1 ]  (bf16, [NN][256]).  (unchanged)
// ---------------------------------------------------------------------------
#define KS 72
__global__ __launch_bounds__(256, 2) void pre1_kernel(
    const float* __restrict__ x, const unsigned short* __restrict__ Wb,
    const float* __restrict__ b1, unsigned short* __restrict__ pq)
{
    __shared__ unsigned short lds[128 * KS + 256 * KS];
    unsigned short* A_s = lds;
    unsigned short* W_s = lds + 128 * KS;

    const int t    = threadIdx.x;
    const int m0   = blockIdx.x * 128;
    const int lane = t & 63;
    const int wave = t >> 6;
    const int lr   = lane & 15;
    const int quad = lane >> 4;
    const int nw0  = wave * 64;

    v4f acc[8][4];
    #pragma unroll
    for (int mt = 0; mt < 8; ++mt)
        #pragma unroll
        for (int nt = 0; nt < 4; ++nt)
            acc[mt][nt] = (v4f){0.f, 0.f, 0.f, 0.f};

    #pragma unroll
    for (int ph = 0; ph < 2; ++ph) {
        const int kh = ph * 64;
        if (ph) __syncthreads();

        {
            const int mi = t & 127;
            const int ko = (t >> 7) * 32;
            const int m  = m0 + mi;
            unsigned short* dp = &A_s[mi * KS + ko];
            if (m < NN) {
                const float4* sp = (const float4*)(x + (size_t)m * F + kh + ko);
                #pragma unroll
                for (int j = 0; j < 8; j += 2) {
                    const float4 f0 = sp[j], f1 = sp[j + 1];
                    uint4 o;
                    o.x = pack2(f0.x, f0.y); o.y = pack2(f0.z, f0.w);
                    o.z = pack2(f1.x, f1.y); o.w = pack2(f1.z, f1.w);
                    *(uint4*)(dp + j * 4) = o;
                }
            } else {
                #pragma unroll
                for (int j = 0; j < 4; ++j)
                    *(uint4*)(dp + j * 8) = make_uint4(0u, 0u, 0u, 0u);
            }
        }
        {
            const unsigned short* sp = Wb + (size_t)t * 128 + kh;
            unsigned short* dp = &W_s[t * KS];
            #pragma unroll
            for (int j = 0; j < 8; ++j)
                *(uint4*)(dp + j * 8) = *(const uint4*)(sp + j * 8);
        }
        __syncthreads();

        #pragma unroll
        for (int ks = 0; ks < 2; ++ks) {
            const int k0 = ks * 32 + quad * 8;
            const v8s b0 = *(const v8s*)&W_s[(nw0 +  0 + lr) * KS + k0];
            const v8s b1v= *(const v8s*)&W_s[(nw0 + 16 + lr) * KS + k0];
            const v8s b2 = *(const v8s*)&W_s[(nw0 + 32 + lr) * KS + k0];
            const v8s b3 = *(const v8s*)&W_s[(nw0 + 48 + lr) * KS + k0];
            #pragma unroll
            for (int mt = 0; mt < 8; ++mt) {
                const v8s a = *(const v8s*)&A_s[(mt * 16 + lr) * KS + k0];
                acc[mt][0] = __builtin_amdgcn_mfma_f32_16x16x32_bf16(a, b0,  acc[mt][0], 0, 0, 0);
                acc[mt][1] = __builtin_amdgcn_mfma_f32_16x16x32_bf16(a, b1v, acc[mt][1], 0, 0, 0);
                acc[mt][2] = __builtin_amdgcn_mfma_f32_16x16x32_bf16(a, b2,  acc[mt][2], 0, 0, 0);
                acc[mt][3] = __builtin_amdgcn_mfma_f32_16x16x32_bf16(a, b3,  acc[mt][3], 0, 0, 0);
            }
        }
        __syncthreads();
    }

    float bias[4];
    #pragma unroll
    for (int nt = 0; nt < 4; ++nt) {
        const int n = nw0 + nt * 16 + lr;
        bias[nt] = (n >= 128) ? b1[n - 128] : 0.0f;
    }

    unsigned short* C_s = lds;
    #pragma unroll
    for (int p = 0; p < 2; ++p) {
        if ((nw0 >> 7) == p) {
            #pragma unroll
            for (int mt = 0; mt < 8; ++mt)
                #pragma unroll
                for (int nt = 0; nt < 4; ++nt) {
                    const int n = (nw0 & 127) + nt * 16 + lr;
                    #pragma unroll
                    for (int r = 0; r < 4; ++r) {
                        const int m = mt * 16 + quad * 4 + r;
                        C_s[m * 136 + n] = f2bf(acc[mt][nt][r] + bias[nt]);
                    }
                }
        }
        __syncthreads();
        {
            const int mi = t & 127;
            const int nh = (t >> 7) * 64;
            const int m  = m0 + mi;
            if (m < NN) {
                unsigned short* dp = pq + (size_t)m * 256 + p * 128 + nh;
                const unsigned short* sp = &C_s[mi * 136 + nh];
                #pragma unroll
                for (int j = 0; j < 8; ++j)
                    *(uint4*)(dp + j * 8) = *(const uint4*)(sp + j * 8);
            }
        }
        __syncthreads();
    }
}

// ---------------------------------------------------------------------------
// agg1d: windowed scatter-aggregation. One block per 128-node window; LDS
// fp32 accumulator [128][132]; entries gathered 256B-coalesced (16 lanes x
// uint4 per entry) and added via LDS float atomics. Degree counted in LDS ->
// invdeg (global, reused by agg2d). Epilogue: hb = relu(acc*inv + q).
// ---------------------------------------------------------------------------
__global__ __launch_bounds__(256) void agg1d_kernel(
    const unsigned short* __restrict__ pq, const unsigned* __restrict__ bucket,
    const int* __restrict__ wcur, unsigned short* __restrict__ hb,
    float* __restrict__ invdeg)
{
    __shared__ float acc[WIN * ACCS];   // 67.6 KB
    __shared__ int dcnt[WIN];
    const int t  = threadIdx.x;
    const int wb = blockIdx.x;
    for (int i = t; i < WIN * ACCS; i += 256) acc[i] = 0.0f;
    if (t < WIN) dcnt[t] = 0;
    __syncthreads();

    const int cntw = min(wcur[wb], WCAP);
    const unsigned* bp = bucket + (size_t)wb * WCAP;
    const int sub = t >> 4;    // entry slot 0..15
    const int g   = t & 15;    // 8-col group

    int i0 = 0;
    for (; i0 + 64 <= cntw; i0 += 64) {
        const unsigned e0 = bp[i0 +  0 + sub];
        const unsigned e1 = bp[i0 + 16 + sub];
        const unsigned e2 = bp[i0 + 32 + sub];
        const unsigned e3 = bp[i0 + 48 + sub];
        const uint4 u0 = *(const uint4*)(pq + (size_t)(e0 & 0x1FFFFu) * 256 + g * 8);
        const uint4 u1 = *(const uint4*)(pq + (size_t)(e1 & 0x1FFFFu) * 256 + g * 8);
        const uint4 u2 = *(const uint4*)(pq + (size_t)(e2 & 0x1FFFFu) * 256 + g * 8);
        const uint4 u3 = *(const uint4*)(pq + (size_t)(e3 & 0x1FFFFu) * 256 + g * 8);
        if (g == 0) {
            atomicAdd(&dcnt[e0 >> 17], 1);
            atomicAdd(&dcnt[e1 >> 17], 1);
            atomicAdd(&dcnt[e2 >> 17], 1);
            atomicAdd(&dcnt[e3 >> 17], 1);
        }
        atomic_acc8(&acc[(e0 >> 17) * ACCS + g * 8], u0);
        atomic_acc8(&acc[(e1 >> 17) * ACCS + g * 8], u1);
        atomic_acc8(&acc[(e2 >> 17) * ACCS + g * 8], u2);
        atomic_acc8(&acc[(e3 >> 17) * ACCS + g * 8], u3);
    }
    for (; i0 < cntw; i0 += 16) {
        const int i = i0 + sub;
        if (i < cntw) {
            const unsigned e = bp[i];
            const uint4 u = *(const uint4*)(pq + (size_t)(e & 0x1FFFFu) * 256 + g * 8);
            if (g == 0) atomicAdd(&dcnt[e >> 17], 1);
            atomic_acc8(&acc[(e >> 17) * ACCS + g * 8], u);
        }
    }
    __syncthreads();

    // epilogue: 2 threads per node, 64 cols each
    const int nloc = t >> 1;
    const int half = t & 1;
    const int n    = wb * WIN + nloc;
    if (n < NN) {
        const float inv = 1.0f / (float)max(dcnt[nloc], 1);
        if (half == 0) invdeg[n] = inv;
        #pragma unroll
        for (int k = 0; k < 8; ++k) {
            const int c = half * 64 + k * 8;
            const float4 a0 = *(const float4*)&acc[nloc * ACCS + c];
            const float4 a1 = *(const float4*)&acc[nloc * ACCS + c + 4];
            const uint4 uq = *(const uint4*)(pq + (size_t)n * 256 + 128 + c);
            float q0, q1, q2, q3, q4, q5, q6, q7;
            unpack2(uq.x, q0, q1); unpack2(uq.y, q2, q3);
            unpack2(uq.z, q4, q5); unpack2(uq.w, q6, q7);
            uint4 o;
            o.x = pack2(fmaxf(a0.x * inv + q0, 0.f), fmaxf(a0.y * inv + q1, 0.f));
            o.y = pack2(fmaxf(a0.z * inv + q2, 0.f), fmaxf(a0.w * inv + q3, 0.f));
            o.z = pack2(fmaxf(a1.x * inv + q4, 0.f), fmaxf(a1.y * inv + q5, 0.f));
            o.w = pack2(fmaxf(a1.z * inv + q6, 0.f), fmaxf(a1.w * inv + q7, 0.f));
            *(uint4*)(hb + (size_t)n * F + c) = o;
        }
    }
}

// ---------------------------------------------------------------------------
// pre2: [z | r] = hb @ [W2l | W2r]; z bf16 [NN][16], r fp32 [NN][16] + bias.
// (unchanged)
// ---------------------------------------------------------------------------
__global__ __launch_bounds__(256, 2) void pre2_kernel(
    const unsigned short* __restrict__ hb,
    const float* __restrict__ W2l, const float* __restrict__ W2r,
    const float* __restrict__ b2,
    unsigned short* __restrict__ z, float* __restrict__ r)
{
    __shared__ unsigned short A_s[128 * 128];
    __shared__ unsigned short W_s[128 * 32];

    const int t  = threadIdx.x;
    const int m0 = blockIdx.x * 128;

    {
        const int mloc = t & 127;
        const int kc   = (t >> 7) * 64;
        const int m    = m0 + mloc;
        #pragma unroll
        for (int j = 0; j < 8; ++j) {
            const int k = kc + j * 8;
            uint4 u = make_uint4(0u, 0u, 0u, 0u);
            if (m < NN) u = *(const uint4*)(hb + (size_t)m * F + k);
            A_s[(k + 0) * 128 + mloc] = (unsigned short)(u.x & 0xffffu);
            A_s[(k + 1) * 128 + mloc] = (unsigned short)(u.x >> 16);
            A_s[(k + 2) * 128 + mloc] = (unsigned short)(u.y & 0xffffu);
            A_s[(k + 3) * 128 + mloc] = (unsigned short)(u.y >> 16);
            A_s[(k + 4) * 128 + mloc] = (unsigned short)(u.z & 0xffffu);
            A_s[(k + 5) * 128 + mloc] = (unsigned short)(u.z >> 16);
            A_s[(k + 6) * 128 + mloc] = (unsigned short)(u.w & 0xffffu);
            A_s[(k + 7) * 128 + mloc] = (unsigned short)(u.w >> 16);
        }
    }
    #pragma unroll
    for (int rr = 0; rr < 16; ++rr) {
        const int idx = rr * 256 + t;
        const int k = idx >> 5;
        const int c = idx & 31;
        float wv = 0.0f;
        if (c < 16) { if (c < C_OUT) wv = W2l[k * C_OUT + c]; }
        else        { if (c - 16 < C_OUT) wv = W2r[k * C_OUT + (c - 16)]; }
        W_s[k * 32 + c] = f2bf(wv);
    }
    __syncthreads();

    const int mq = t & 31;
    const int nq = t >> 5;
    float acc[4][4];
    #pragma unroll
    for (int i = 0; i < 4; ++i)
        #pragma unroll
        for (int j = 0; j < 4; ++j) acc[i][j] = 0.0f;

    #pragma unroll 4
    for (int k = 0; k < 128; ++k) {
        const uint2 ua = *(const uint2*)&A_s[k * 128 + mq * 4];
        const uint2 uw = *(const uint2*)&W_s[k * 32 + nq * 4];
        float a[4], w[4];
        unpack2(ua.x, a[0], a[1]); unpack2(ua.y, a[2], a[3]);
        unpack2(uw.x, w[0], w[1]); unpack2(uw.y, w[2], w[3]);
        #pragma unroll
        for (int i = 0; i < 4; ++i)
            #pragma unroll
            for (int j = 0; j < 4; ++j)
                acc[i][j] += a[i] * w[j];
    }

    const int c0 = nq * 4;
    #pragma unroll
    for (int i = 0; i < 4; ++i) {
        const int m = m0 + mq * 4 + i;
        if (m < NN) {
            if (nq < 4) {
                uint2 o;
                o.x = pack2(acc[i][0], acc[i][1]);
                o.y = pack2(acc[i][2], acc[i][3]);
                *(uint2*)(z + (size_t)m * ZP + c0) = o;
            } else {
                const int rc = c0 - 16;
                float4 o;
                o.x = acc[i][0] + ((rc + 0 < C_OUT) ? b2[rc + 0] : 0.0f);
                o.y = acc[i][1] + ((rc + 1 < C_OUT) ? b2[rc + 1] : 0.0f);
                o.z = acc[i][2] + ((rc + 2 < C_OUT) ? b2[rc + 2] : 0.0f);
                o.w = acc[i][3] + ((rc + 3 < C_OUT) ? b2[rc + 3] : 0.0f);
                *(float4*)(r + (size_t)m * ZP + rc) = o;
            }
        }
    }
}

// ---------------------------------------------------------------------------
// agg2d: windowed scatter over z (32B rows) + fused dual log_softmax.
// Reuses the SAME bucket as agg1d. acc [128][20] fp32 (10 KB).
// ---------------------------------------------------------------------------
#define ACC2S 20
__global__ __launch_bounds__(256) void agg2d_kernel(
    const unsigned short* __restrict__ z, const float* __restrict__ r,
    const unsigned* __restrict__ bucket, const int* __restrict__ wcur,
    const float* __restrict__ invdeg, const int* __restrict__ sf_ptr,
    float* __restrict__ out)
{
    __shared__ float acc[WIN * ACC2S];   // 10.2 KB
    const int t  = threadIdx.x;
    const int wb = blockIdx.x;
    for (int i = t; i < WIN * ACC2S; i += 256) acc[i] = 0.0f;
    __syncthreads();

    const int cntw = min(wcur[wb], WCAP);
    const unsigned* bp = bucket + (size_t)wb * WCAP;
    const int sub = t >> 1;     // entry slot 0..127
    const int g2  = t & 1;      // 8-col half

    int i0 = 0;
    for (; i0 + 256 <= cntw; i0 += 256) {
        const unsigned e0 = bp[i0 + sub];
        const unsigned e1 = bp[i0 + 128 + sub];
        const uint4 u0 = *(const uint4*)(z + (size_t)(e0 & 0x1FFFFu) * ZP + g2 * 8);
        const uint4 u1 = *(const uint4*)(z + (size_t)(e1 & 0x1FFFFu) * ZP + g2 * 8);
        atomic_acc8(&acc[(e0 >> 17) * ACC2S + g2 * 8], u0);
        atomic_acc8(&acc[(e1 >> 17) * ACC2S + g2 * 8], u1);
    }
    for (; i0 < cntw; i0 += 128) {
        const int i = i0 + sub;
        if (i < cntw) {
            const unsigned e = bp[i];
            const uint4 u = *(const uint4*)(z + (size_t)(e & 0x1FFFFu) * ZP + g2 * 8);
            atomic_acc8(&acc[(e >> 17) * ACC2S + g2 * 8], u);
        }
    }
    __syncthreads();

    if (t < WIN) {
        const int n = wb * WIN + t;
        if (n < NN) {
            const float inv = invdeg[n];
            float row[C_OUT];
            #pragma unroll
            for (int c = 0; c < C_OUT; ++c)
                row[c] = acc[t * ACC2S + c] * inv + r[(size_t)n * ZP + c];
            const int sf = *sf_ptr;
            float m = -1e30f;
            for (int c = 0; c < sf; ++c) m = fmaxf(m, row[c]);
            float s = 0.0f;
            for (int c = 0; c < sf; ++c) s += expf(row[c] - m);
            float ls = m + logf(s);
            for (int c = 0; c < sf; ++c)
                out[(long long)n * sf + c] = row[c] - ls;
            m = -1e30f;
            for (int c = sf; c < C_OUT; ++c) m = fmaxf(m, row[c]);
            s = 0.0f;
            for (int c = sf; c < C_OUT; ++c) s += expf(row[c] - m);
            ls = m + logf(s);
            const int pt = C_OUT - sf;
            for (int c = sf; c < C_OUT; ++c)
                out[(long long)NN * sf + (long long)n * pt + (c - sf)] = row[c] - ls;
        }
    }
}

// ---------------------------------------------------------------------------
extern "C" void kernel_launch(void* const* d_in, const int* in_sizes, int n_in,
                              void* d_out, int out_size, void* d_ws, size_t ws_size,
                              hipStream_t stream)
{
    const float* x   = (const float*)d_in[0];
    const int*   ei  = (const int*)d_in[1];
    const int*   sfp = (const int*)d_in[2];
    const float* W1l = (const float*)d_in[3];
    const float* W1r = (const float*)d_in[4];
    const float* b1  = (const float*)d_in[5];
    const float* W2l = (const float*)d_in[6];
    const float* W2r = (const float*)d_in[7];
    const float* b2  = (const float*)d_in[8];
    float*       out = (float*)d_out;

    const int E = in_sizes[1] / 2;
    const int* src = ei;
    const int* dst = ei + E;

    // ws layout (words). bucket lives bin->agg2d (own region); z/r alias pq
    // (pq dead after agg1d).
    int*      wcur   = (int*)d_ws;                           // 1024 (NWIN used)
    float*    invdeg = (float*)(wcur + 1024);                // NN
    unsigned* bucket = (unsigned*)(invdeg + NN);             // NWIN*WCAP (~8 MB)
    unsigned short* Wb = (unsigned short*)(bucket + (size_t)NWIN * WCAP); // 32768
    unsigned short* hb = Wb + 2 * 128 * 128;                 // NN*F bf16
    unsigned short* pq = hb + (size_t)NN * F;                // NN*256 bf16
    unsigned short* z  = pq;                                 // alias: NN*16 bf16
    float*          r  = (float*)(pq + (size_t)NN * ZP);     // NN*16 fp32

    hipMemsetAsync(wcur, 0, 1024 * sizeof(int), stream);

    // edge binning into 128-node windows (replaces entire CSR build)
    bin_kernel<<<(E + EBATCH - 1) / EBATCH, 256, 0, stream>>>(src, dst, bucket, wcur, E);

    // weight prep + layer-1 GEMM (MFMA)
    wprep_kernel<<<128, 256, 0, stream>>>(W1l, W1r, Wb);
    pre1_kernel<<<(NN + 127) / 128, 256, 0, stream>>>(x, Wb, b1, pq);

    // layer-1 aggregation (windowed LDS scatter) -> hb, invdeg
    agg1d_kernel<<<NWIN, 256, 0, stream>>>(pq, bucket, wcur, hb, invdeg);

    // layer-2 GEMM + aggregation + softmax
    pre2_kernel<<<(NN + 127) / 128, 256, 0, stream>>>(hb, W2l, W2r, b2, z, r);
    agg2d_kernel<<<NWIN, 256, 0, stream>>>(z, r, bucket, wcur, invdeg, sfp, out);
}

// Round 10
// 283.392 us; speedup vs baseline: 5.9944x; 5.9944x over previous
//
#include <hip/hip_runtime.h>
#include <hip/hip_bf16.h>

#define NN 100000
#define F 128
#define C_OUT 14
#define ZP 16
#define WIN 64
#define NWIN ((NN + WIN - 1) / WIN)    // 1563 windows of 64 nodes
#define WCAP 1408                      // mean 1024, +12 sigma
#define EBATCH 4096

typedef __attribute__((ext_vector_type(8))) short v8s;   // 8 bf16 (4 VGPRs)
typedef __attribute__((ext_vector_type(4))) float v4f;   // 4 fp32 acc

// ---------------- bf16 helpers ----------------------------------------------
static __device__ __forceinline__ unsigned short f2bf(float f) {
    unsigned int u = __float_as_uint(f);
    unsigned int r = (u + 0x7fffu + ((u >> 16) & 1u)) >> 16;   // RTN-even
    return (unsigned short)r;
}
static __device__ __forceinline__ unsigned int pack2(float a, float b) {
    return (unsigned int)f2bf(a) | ((unsigned int)f2bf(b) << 16);
}
static __device__ __forceinline__ void unpack2(unsigned int u, float& lo, float& hi) {
    lo = __uint_as_float(u << 16);
    hi = __uint_as_float(u & 0xffff0000u);
}

// ---------------------------------------------------------------------------
// bin: single pass over edges -> 1563 window buckets of 4B entries
// (ent = dloc<<17 | src, dloc<64, src<2^17). Per-block LDS counts, ONE global
// cursor claim per (block,window), contiguous range writes. (R9: proven fine.)
// ---------------------------------------------------------------------------
__global__ __launch_bounds__(256) void bin_kernel(
    const int* __restrict__ src, const int* __restrict__ dst,
    unsigned* __restrict__ bucket, int* __restrict__ wcur, int E)
{
    __shared__ int cnt_s[NWIN];     // 6.25 KB
    __shared__ int gbase_s[NWIN];   // 6.25 KB
    const int t = threadIdx.x;
    for (int w = t; w < NWIN; w += 256) cnt_s[w] = 0;
    __syncthreads();

    int      wreg[16];
    unsigned ereg[16];
    const int e0 = blockIdx.x * EBATCH;
    #pragma unroll
    for (int j = 0; j < 16; ++j) {
        const int e = e0 + j * 256 + t;
        int w = -1; unsigned ent = 0;
        if (e < E) {
            const int d = dst[e];
            const int s = src[e];
            w   = d >> 6;
            ent = ((unsigned)(d & (WIN - 1)) << 17) | (unsigned)s;
            atomicAdd(&cnt_s[w], 1);
        }
        wreg[j] = w; ereg[j] = ent;
    }
    __syncthreads();
    for (int w = t; w < NWIN; w += 256) {
        const int c = cnt_s[w];
        gbase_s[w] = c ? atomicAdd(&wcur[w], c) : 0;
    }
    __syncthreads();
    for (int w = t; w < NWIN; w += 256) cnt_s[w] = 0;   // reuse as local cursor
    __syncthreads();
    #pragma unroll
    for (int j = 0; j < 16; ++j) {
        const int w = wreg[j];
        if (w >= 0) {
            const int pos = gbase_s[w] + atomicAdd(&cnt_s[w], 1);
            if (pos < WCAP) bucket[(size_t)w * WCAP + pos] = ereg[j];
        }
    }
}

// ---------------------------------------------------------------------------
// wprep: Wb[n][k] = bf16 of [W1l | W1r] transposed.
// ---------------------------------------------------------------------------
__global__ __launch_bounds__(256) void wprep_kernel(
    const float* __restrict__ W1l, const float* __restrict__ W1r,
    unsigned short* __restrict__ Wb)
{
    const int idx = blockIdx.x * 256 + threadIdx.x;
    if (idx >= 2 * 128 * 128) return;
    const int c   = idx >> 14;
    const int rem = idx & 16383;
    const int n   = rem >> 7;
    const int k   = rem & 127;
    const float* W = c ? W1r : W1l;
    Wb[idx] = f2bf(W[k * 128 + n]);
}

// ---------------------------------------------------------------------------
// pre1 (MFMA): pq = [ x@W1l | x@W1r + b1 ]  (bf16, [NN][256]).  (unchanged)
// ---------------------------------------------------------------------------
#define KS 72
__global__ __launch_bounds__(256, 2) void pre1_kernel(
    const float* __restrict__ x, const unsigned short* __restrict__ Wb,
    const float* __restrict__ b1, unsigned short* __restrict__ pq)
{
    __shared__ unsigned short lds[128 * KS + 256 * KS];
    unsigned short* A_s = lds;
    unsigned short* W_s = lds + 128 * KS;

    const int t    = threadIdx.x;
    const int m0   = blockIdx.x * 128;
    const int lane = t & 63;
    const int wave = t >> 6;
    const int lr   = lane & 15;
    const int quad = lane >> 4;
    const int nw0  = wave * 64;

    v4f acc[8][4];
    #pragma unroll
    for (int mt = 0; mt < 8; ++mt)
        #pragma unroll
        for (int nt = 0; nt < 4; ++nt)
            acc[mt][nt] = (v4f){0.f, 0.f, 0.f, 0.f};

    #pragma unroll
    for (int ph = 0; ph < 2; ++ph) {
        const int kh = ph * 64;
        if (ph) __syncthreads();

        {
            const int mi = t & 127;
            const int ko = (t >> 7) * 32;
            const int m  = m0 + mi;
            unsigned short* dp = &A_s[mi * KS + ko];
            if (m < NN) {
                const float4* sp = (const float4*)(x + (size_t)m * F + kh + ko);
                #pragma unroll
                for (int j = 0; j < 8; j += 2) {
                    const float4 f0 = sp[j], f1 = sp[j + 1];
                    uint4 o;
                    o.x = pack2(f0.x, f0.y); o.y = pack2(f0.z, f0.w);
                    o.z = pack2(f1.x, f1.y); o.w = pack2(f1.z, f1.w);
                    *(uint4*)(dp + j * 4) = o;
                }
            } else {
                #pragma unroll
                for (int j = 0; j < 4; ++j)
                    *(uint4*)(dp + j * 8) = make_uint4(0u, 0u, 0u, 0u);
            }
        }
        {
            const unsigned short* sp = Wb + (size_t)t * 128 + kh;
            unsigned short* dp = &W_s[t * KS];
            #pragma unroll
            for (int j = 0; j < 8; ++j)
                *(uint4*)(dp + j * 8) = *(const uint4*)(sp + j * 8);
        }
        __syncthreads();

        #pragma unroll
        for (int ks = 0; ks < 2; ++ks) {
            const int k0 = ks * 32 + quad * 8;
            const v8s b0 = *(const v8s*)&W_s[(nw0 +  0 + lr) * KS + k0];
            const v8s b1v= *(const v8s*)&W_s[(nw0 + 16 + lr) * KS + k0];
            const v8s b2 = *(const v8s*)&W_s[(nw0 + 32 + lr) * KS + k0];
            const v8s b3 = *(const v8s*)&W_s[(nw0 + 48 + lr) * KS + k0];
            #pragma unroll
            for (int mt = 0; mt < 8; ++mt) {
                const v8s a = *(const v8s*)&A_s[(mt * 16 + lr) * KS + k0];
                acc[mt][0] = __builtin_amdgcn_mfma_f32_16x16x32_bf16(a, b0,  acc[mt][0], 0, 0, 0);
                acc[mt][1] = __builtin_amdgcn_mfma_f32_16x16x32_bf16(a, b1v, acc[mt][1], 0, 0, 0);
                acc[mt][2] = __builtin_amdgcn_mfma_f32_16x16x32_bf16(a, b2,  acc[mt][2], 0, 0, 0);
                acc[mt][3] = __builtin_amdgcn_mfma_f32_16x16x32_bf16(a, b3,  acc[mt][3], 0, 0, 0);
            }
        }
        __syncthreads();
    }

    float bias[4];
    #pragma unroll
    for (int nt = 0; nt < 4; ++nt) {
        const int n = nw0 + nt * 16 + lr;
        bias[nt] = (n >= 128) ? b1[n - 128] : 0.0f;
    }

    unsigned short* C_s = lds;
    #pragma unroll
    for (int p = 0; p < 2; ++p) {
        if ((nw0 >> 7) == p) {
            #pragma unroll
            for (int mt = 0; mt < 8; ++mt)
                #pragma unroll
                for (int nt = 0; nt < 4; ++nt) {
                    const int n = (nw0 & 127) + nt * 16 + lr;
                    #pragma unroll
                    for (int r = 0; r < 4; ++r) {
                        const int m = mt * 16 + quad * 4 + r;
                        C_s[m * 136 + n] = f2bf(acc[mt][nt][r] + bias[nt]);
                    }
                }
        }
        __syncthreads();
        {
            const int mi = t & 127;
            const int nh = (t >> 7) * 64;
            const int m  = m0 + mi;
            if (m < NN) {
                unsigned short* dp = pq + (size_t)m * 256 + p * 128 + nh;
                const unsigned short* sp = &C_s[mi * 136 + nh];
                #pragma unroll
                for (int j = 0; j < 8; ++j)
                    *(uint4*)(dp + j * 8) = *(const uint4*)(sp + j * 8);
            }
        }
        __syncthreads();
    }
}

// ---------------------------------------------------------------------------
// agg1s: one block per 64-node window. Build window-local CSR in LDS (int
// counts -> 6-step scan -> scatter; NO float atomics), then R6-style register
// gather: 16-lane groups, uint4/lane (256B coalesced per entry), x4 unroll.
// hb = relu(mean*inv + q). Degree from counts (invdeg array deleted).
// ---------------------------------------------------------------------------
__global__ __launch_bounds__(256) void agg1s_kernel(
    const unsigned short* __restrict__ pq, const unsigned* __restrict__ bucket,
    const int* __restrict__ wcur, unsigned short* __restrict__ hb)
{
    __shared__ unsigned raw[WCAP];      // 5.6 KB
    __shared__ unsigned list[WCAP];     // 5.6 KB
    __shared__ int cnt_s[WIN], base_s[WIN], cur_s[WIN];
    const int t  = threadIdx.x;
    const int wb = blockIdx.x;
    const int cntw = min(wcur[wb], WCAP);
    const unsigned* bp = bucket + (size_t)wb * WCAP;

    if (t < WIN) cnt_s[t] = 0;
    for (int i = t; i < cntw; i += 256) raw[i] = bp[i];
    __syncthreads();
    for (int i = t; i < cntw; i += 256) atomicAdd(&cnt_s[raw[i] >> 17], 1);
    __syncthreads();
    if (t < WIN) base_s[t] = cnt_s[t];
    __syncthreads();
    for (int off = 1; off < WIN; off <<= 1) {
        int v = 0;
        if (t < WIN && t >= off) v = base_s[t - off];
        __syncthreads();
        if (t < WIN) base_s[t] += v;
        __syncthreads();
    }
    if (t < WIN) { const int b = base_s[t] - cnt_s[t]; base_s[t] = b; cur_s[t] = b; }
    __syncthreads();
    for (int i = t; i < cntw; i += 256) {
        const unsigned e = raw[i];
        list[atomicAdd(&cur_s[e >> 17], 1)] = e & 0x1FFFFu;
    }
    __syncthreads();

    const int g    = t >> 4;      // 16 groups
    const int lane = t & 15;
    const int col  = lane * 8;
    #pragma unroll
    for (int rep = 0; rep < 4; ++rep) {
        const int nloc = rep * 16 + g;
        const int n = wb * WIN + nloc;
        if (n >= NN) continue;
        const int start = base_s[nloc];
        const int len   = cnt_s[nloc];
        float a0[8] = {0,0,0,0,0,0,0,0};
        float a1[8] = {0,0,0,0,0,0,0,0};
        float a2[8] = {0,0,0,0,0,0,0,0};
        float a3[8] = {0,0,0,0,0,0,0,0};
        int i = 0;
        for (; i + 4 <= len; i += 4) {
            const int s0 = (int)list[start + i + 0];
            const int s1 = (int)list[start + i + 1];
            const int s2 = (int)list[start + i + 2];
            const int s3 = (int)list[start + i + 3];
            const uint4 u0 = *(const uint4*)(pq + (size_t)s0 * 256 + col);
            const uint4 u1 = *(const uint4*)(pq + (size_t)s1 * 256 + col);
            const uint4 u2 = *(const uint4*)(pq + (size_t)s2 * 256 + col);
            const uint4 u3 = *(const uint4*)(pq + (size_t)s3 * 256 + col);
            float f0, f1;
            unpack2(u0.x, f0, f1); a0[0] += f0; a0[1] += f1;
            unpack2(u0.y, f0, f1); a0[2] += f0; a0[3] += f1;
            unpack2(u0.z, f0, f1); a0[4] += f0; a0[5] += f1;
            unpack2(u0.w, f0, f1); a0[6] += f0; a0[7] += f1;
            unpack2(u1.x, f0, f1); a1[0] += f0; a1[1] += f1;
            unpack2(u1.y, f0, f1); a1[2] += f0; a1[3] += f1;
            unpack2(u1.z, f0, f1); a1[4] += f0; a1[5] += f1;
            unpack2(u1.w, f0, f1); a1[6] += f0; a1[7] += f1;
            unpack2(u2.x, f0, f1); a2[0] += f0; a2[1] += f1;
            unpack2(u2.y, f0, f1); a2[2] += f0; a2[3] += f1;
            unpack2(u2.z, f0, f1); a2[4] += f0; a2[5] += f1;
            unpack2(u2.w, f0, f1); a2[6] += f0; a2[7] += f1;
            unpack2(u3.x, f0, f1); a3[0] += f0; a3[1] += f1;
            unpack2(u3.y, f0, f1); a3[2] += f0; a3[3] += f1;
            unpack2(u3.z, f0, f1); a3[4] += f0; a3[5] += f1;
            unpack2(u3.w, f0, f1); a3[6] += f0; a3[7] += f1;
        }
        for (; i < len; ++i) {
            const int s = (int)list[start + i];
            const uint4 u = *(const uint4*)(pq + (size_t)s * 256 + col);
            float f0, f1;
            unpack2(u.x, f0, f1); a0[0] += f0; a0[1] += f1;
            unpack2(u.y, f0, f1); a0[2] += f0; a0[3] += f1;
            unpack2(u.z, f0, f1); a0[4] += f0; a0[5] += f1;
            unpack2(u.w, f0, f1); a0[6] += f0; a0[7] += f1;
        }
        const float inv = 1.0f / (float)max(len, 1);
        const uint4 uq = *(const uint4*)(pq + (size_t)n * 256 + 128 + col);
        float q[8];
        unpack2(uq.x, q[0], q[1]); unpack2(uq.y, q[2], q[3]);
        unpack2(uq.z, q[4], q[5]); unpack2(uq.w, q[6], q[7]);
        float hv[8];
        #pragma unroll
        for (int j = 0; j < 8; ++j)
            hv[j] = fmaxf((a0[j] + a1[j] + a2[j] + a3[j]) * inv + q[j], 0.0f);
        uint4 o;
        o.x = pack2(hv[0], hv[1]);
        o.y = pack2(hv[2], hv[3]);
        o.z = pack2(hv[4], hv[5]);
        o.w = pack2(hv[6], hv[7]);
        *(uint4*)(hb + (size_t)n * F + col) = o;
    }
}

// ---------------------------------------------------------------------------
// pre2: [z | r] = hb @ [W2l | W2r]; z bf16 [NN][16], r fp32 [NN][16] + bias.
// (unchanged)
// ---------------------------------------------------------------------------
__global__ __launch_bounds__(256, 2) void pre2_kernel(
    const unsigned short* __restrict__ hb,
    const float* __restrict__ W2l, const float* __restrict__ W2r,
    const float* __restrict__ b2,
    unsigned short* __restrict__ z, float* __restrict__ r)
{
    __shared__ unsigned short A_s[128 * 128];
    __shared__ unsigned short W_s[128 * 32];

    const int t  = threadIdx.x;
    const int m0 = blockIdx.x * 128;

    {
        const int mloc = t & 127;
        const int kc   = (t >> 7) * 64;
        const int m    = m0 + mloc;
        #pragma unroll
        for (int j = 0; j < 8; ++j) {
            const int k = kc + j * 8;
            uint4 u = make_uint4(0u, 0u, 0u, 0u);
            if (m < NN) u = *(const uint4*)(hb + (size_t)m * F + k);
            A_s[(k + 0) * 128 + mloc] = (unsigned short)(u.x & 0xffffu);
            A_s[(k + 1) * 128 + mloc] = (unsigned short)(u.x >> 16);
            A_s[(k + 2) * 128 + mloc] = (unsigned short)(u.y & 0xffffu);
            A_s[(k + 3) * 128 + mloc] = (unsigned short)(u.y >> 16);
            A_s[(k + 4) * 128 + mloc] = (unsigned short)(u.z & 0xffffu);
            A_s[(k + 5) * 128 + mloc] = (unsigned short)(u.z >> 16);
            A_s[(k + 6) * 128 + mloc] = (unsigned short)(u.w & 0xffffu);
            A_s[(k + 7) * 128 + mloc] = (unsigned short)(u.w >> 16);
        }
    }
    #pragma unroll
    for (int rr = 0; rr < 16; ++rr) {
        const int idx = rr * 256 + t;
        const int k = idx >> 5;
        const int c = idx & 31;
        float wv = 0.0f;
        if (c < 16) { if (c < C_OUT) wv = W2l[k * C_OUT + c]; }
        else        { if (c - 16 < C_OUT) wv = W2r[k * C_OUT + (c - 16)]; }
        W_s[k * 32 + c] = f2bf(wv);
    }
    __syncthreads();

    const int mq = t & 31;
    const int nq = t >> 5;
    float acc[4][4];
    #pragma unroll
    for (int i = 0; i < 4; ++i)
        #pragma unroll
        for (int j = 0; j < 4; ++j) acc[i][j] = 0.0f;

    #pragma unroll 4
    for (int k = 0; k < 128; ++k) {
        const uint2 ua = *(const uint2*)&A_s[k * 128 + mq * 4];
        const uint2 uw = *(const uint2*)&W_s[k * 32 + nq * 4];
        float a[4], w[4];
        unpack2(ua.x, a[0], a[1]); unpack2(ua.y, a[2], a[3]);
        unpack2(uw.x, w[0], w[1]); unpack2(uw.y, w[2], w[3]);
        #pragma unroll
        for (int i = 0; i < 4; ++i)
            #pragma unroll
            for (int j = 0; j < 4; ++j)
                acc[i][j] += a[i] * w[j];
    }

    const int c0 = nq * 4;
    #pragma unroll
    for (int i = 0; i < 4; ++i) {
        const int m = m0 + mq * 4 + i;
        if (m < NN) {
            if (nq < 4) {
                uint2 o;
                o.x = pack2(acc[i][0], acc[i][1]);
                o.y = pack2(acc[i][2], acc[i][3]);
                *(uint2*)(z + (size_t)m * ZP + c0) = o;
            } else {
                const int rc = c0 - 16;
                float4 o;
                o.x = acc[i][0] + ((rc + 0 < C_OUT) ? b2[rc + 0] : 0.0f);
                o.y = acc[i][1] + ((rc + 1 < C_OUT) ? b2[rc + 1] : 0.0f);
                o.z = acc[i][2] + ((rc + 2 < C_OUT) ? b2[rc + 2] : 0.0f);
                o.w = acc[i][3] + ((rc + 3 < C_OUT) ? b2[rc + 3] : 0.0f);
                *(float4*)(r + (size_t)m * ZP + rc) = o;
            }
        }
    }
}

// ---------------------------------------------------------------------------
// agg2s: same window-local CSR sort, gather z (32B rows, 4 lanes x uint2),
// degree from counts, fused dual log_softmax.
// ---------------------------------------------------------------------------
__global__ __launch_bounds__(256) void agg2s_kernel(
    const unsigned short* __restrict__ z, const float* __restrict__ r,
    const unsigned* __restrict__ bucket, const int* __restrict__ wcur,
    const int* __restrict__ sf_ptr, float* __restrict__ out)
{
    __shared__ unsigned raw[WCAP];
    __shared__ unsigned list[WCAP];
    __shared__ int cnt_s[WIN], base_s[WIN], cur_s[WIN];
    __shared__ float sm[WIN][ZP + 1];
    const int t  = threadIdx.x;
    const int wb = blockIdx.x;
    const int cntw = min(wcur[wb], WCAP);
    const unsigned* bp = bucket + (size_t)wb * WCAP;

    if (t < WIN) cnt_s[t] = 0;
    for (int i = t; i < cntw; i += 256) raw[i] = bp[i];
    __syncthreads();
    for (int i = t; i < cntw; i += 256) atomicAdd(&cnt_s[raw[i] >> 17], 1);
    __syncthreads();
    if (t < WIN) base_s[t] = cnt_s[t];
    __syncthreads();
    for (int off = 1; off < WIN; off <<= 1) {
        int v = 0;
        if (t < WIN && t >= off) v = base_s[t - off];
        __syncthreads();
        if (t < WIN) base_s[t] += v;
        __syncthreads();
    }
    if (t < WIN) { const int b = base_s[t] - cnt_s[t]; base_s[t] = b; cur_s[t] = b; }
    __syncthreads();
    for (int i = t; i < cntw; i += 256) {
        const unsigned e = raw[i];
        list[atomicAdd(&cur_s[e >> 17], 1)] = e & 0x1FFFFu;
    }
    __syncthreads();

    const int g  = t >> 2;      // node slot 0..63
    const int j4 = (t & 3) * 4;
    const int n  = wb * WIN + g;
    if (n < NN) {
        const int start = base_s[g];
        const int len   = cnt_s[g];
        float4 a0 = make_float4(0.f, 0.f, 0.f, 0.f);
        float4 a1 = a0, a2 = a0, a3 = a0;
        int i = 0;
        for (; i + 4 <= len; i += 4) {
            const int s0 = (int)list[start + i + 0];
            const int s1 = (int)list[start + i + 1];
            const int s2 = (int)list[start + i + 2];
            const int s3 = (int)list[start + i + 3];
            const uint2 u0 = *(const uint2*)(z + (size_t)s0 * ZP + j4);
            const uint2 u1 = *(const uint2*)(z + (size_t)s1 * ZP + j4);
            const uint2 u2 = *(const uint2*)(z + (size_t)s2 * ZP + j4);
            const uint2 u3 = *(const uint2*)(z + (size_t)s3 * ZP + j4);
            float f0, f1, f2, f3;
            unpack2(u0.x, f0, f1); unpack2(u0.y, f2, f3);
            a0.x += f0; a0.y += f1; a0.z += f2; a0.w += f3;
            unpack2(u1.x, f0, f1); unpack2(u1.y, f2, f3);
            a1.x += f0; a1.y += f1; a1.z += f2; a1.w += f3;
            unpack2(u2.x, f0, f1); unpack2(u2.y, f2, f3);
            a2.x += f0; a2.y += f1; a2.z += f2; a2.w += f3;
            unpack2(u3.x, f0, f1); unpack2(u3.y, f2, f3);
            a3.x += f0; a3.y += f1; a3.z += f2; a3.w += f3;
        }
        for (; i < len; ++i) {
            const int s = (int)list[start + i];
            const uint2 u = *(const uint2*)(z + (size_t)s * ZP + j4);
            float f0, f1, f2, f3;
            unpack2(u.x, f0, f1); unpack2(u.y, f2, f3);
            a0.x += f0; a0.y += f1; a0.z += f2; a0.w += f3;
        }
        const float inv = 1.0f / (float)max(len, 1);
        const float4 rv = *(const float4*)(r + (size_t)n * ZP + j4);
        sm[g][j4 + 0] = (a0.x + a1.x + a2.x + a3.x) * inv + rv.x;
        sm[g][j4 + 1] = (a0.y + a1.y + a2.y + a3.y) * inv + rv.y;
        sm[g][j4 + 2] = (a0.z + a1.z + a2.z + a3.z) * inv + rv.z;
        sm[g][j4 + 3] = (a0.w + a1.w + a2.w + a3.w) * inv + rv.w;
    }
    __syncthreads();

    if (t < WIN) {
        const int n2 = wb * WIN + t;
        if (n2 < NN) {
            const int sf = *sf_ptr;
            const float* row = sm[t];
            float m = -1e30f;
            for (int c = 0; c < sf; ++c) m = fmaxf(m, row[c]);
            float s = 0.0f;
            for (int c = 0; c < sf; ++c) s += expf(row[c] - m);
            float ls = m + logf(s);
            for (int c = 0; c < sf; ++c)
                out[(long long)n2 * sf + c] = row[c] - ls;
            m = -1e30f;
            for (int c = sf; c < C_OUT; ++c) m = fmaxf(m, row[c]);
            s = 0.0f;
            for (int c = sf; c < C_OUT; ++c) s += expf(row[c] - m);
            ls = m + logf(s);
            const int pt = C_OUT - sf;
            for (int c = sf; c < C_OUT; ++c)
                out[(long long)NN * sf + (long long)n2 * pt + (c - sf)] = row[c] - ls;
        }
    }
}

// ---------------------------------------------------------------------------
extern "C" void kernel_launch(void* const* d_in, const int* in_sizes, int n_in,
                              void* d_out, int out_size, void* d_ws, size_t ws_size,
                              hipStream_t stream)
{
    const float* x   = (const float*)d_in[0];
    const int*   ei  = (const int*)d_in[1];
    const int*   sfp = (const int*)d_in[2];
    const float* W1l = (const float*)d_in[3];
    const float* W1r = (const float*)d_in[4];
    const float* b1  = (const float*)d_in[5];
    const float* W2l = (const float*)d_in[6];
    const float* W2r = (const float*)d_in[7];
    const float* b2  = (const float*)d_in[8];
    float*       out = (float*)d_out;

    const int E = in_sizes[1] / 2;
    const int* src = ei;
    const int* dst = ei + E;

    // ws layout (words). bucket lives bin->agg2s; z/r alias pq after agg1s.
    int*      wcur   = (int*)d_ws;                            // NWIN (pad 2048)
    unsigned* bucket = (unsigned*)(wcur + 2048);              // NWIN*WCAP (~8.8 MB)
    unsigned short* Wb = (unsigned short*)(bucket + (size_t)NWIN * WCAP); // 32768
    unsigned short* hb = Wb + 2 * 128 * 128;                  // NN*F bf16
    unsigned short* pq = hb + (size_t)NN * F;                 // NN*256 bf16
    unsigned short* z  = pq;                                  // alias
    float*          r  = (float*)(pq + (size_t)NN * ZP);      // after z

    hipMemsetAsync(wcur, 0, 2048 * sizeof(int), stream);

    // edge binning into 64-node windows (replaces entire CSR build)
    bin_kernel<<<(E + EBATCH - 1) / EBATCH, 256, 0, stream>>>(src, dst, bucket, wcur, E);

    // weight prep + layer-1 GEMM (MFMA)
    wprep_kernel<<<128, 256, 0, stream>>>(W1l, W1r, Wb);
    pre1_kernel<<<(NN + 127) / 128, 256, 0, stream>>>(x, Wb, b1, pq);

    // layer-1 aggregation: window-local LDS CSR + register gather
    agg1s_kernel<<<NWIN, 256, 0, stream>>>(pq, bucket, wcur, hb);

    // layer-2 GEMM + aggregation + softmax
    pre2_kernel<<<(NN + 127) / 128, 256, 0, stream>>>(hb, W2l, W2r, b2, z, r);
    agg2s_kernel<<<NWIN, 256, 0, stream>>>(z, r, bucket, wcur, sfp, out);
}

// Round 11
// 259.360 us; speedup vs baseline: 6.5498x; 1.0927x over previous
//
#include <hip/hip_runtime.h>
#include <hip/hip_bf16.h>

#define NN 100000
#define F 128
#define C_OUT 14
#define ZP 16
#define WIN 64
#define NWIN ((NN + WIN - 1) / WIN)    // 1563 windows of 64 nodes
#define WCAP 1408                      // mean 1024, +12 sigma
#define EBATCH 4096
#define HS 136                         // hsm stride (shorts): 16B-aligned, 8-way max

typedef __attribute__((ext_vector_type(8))) short v8s;   // 8 bf16 (4 VGPRs)
typedef __attribute__((ext_vector_type(4))) float v4f;   // 4 fp32 acc

// ---------------- bf16 helpers ----------------------------------------------
static __device__ __forceinline__ unsigned short f2bf(float f) {
    unsigned int u = __float_as_uint(f);
    unsigned int r = (u + 0x7fffu + ((u >> 16) & 1u)) >> 16;   // RTN-even
    return (unsigned short)r;
}
static __device__ __forceinline__ unsigned int pack2(float a, float b) {
    return (unsigned int)f2bf(a) | ((unsigned int)f2bf(b) << 16);
}
static __device__ __forceinline__ void unpack2(unsigned int u, float& lo, float& hi) {
    lo = __uint_as_float(u << 16);
    hi = __uint_as_float(u & 0xffff0000u);
}

// ---------------------------------------------------------------------------
// bin: single pass over edges -> window buckets of 4B entries
// (ent = dloc<<17 | src). Per-block LDS counts, ONE global cursor claim per
// (block,window), contiguous range writes. (proven R9/R10)
// ---------------------------------------------------------------------------
__global__ __launch_bounds__(256) void bin_kernel(
    const int* __restrict__ src, const int* __restrict__ dst,
    unsigned* __restrict__ bucket, int* __restrict__ wcur, int E)
{
    __shared__ int cnt_s[NWIN];
    __shared__ int gbase_s[NWIN];
    const int t = threadIdx.x;
    for (int w = t; w < NWIN; w += 256) cnt_s[w] = 0;
    __syncthreads();

    int      wreg[16];
    unsigned ereg[16];
    const int e0 = blockIdx.x * EBATCH;
    #pragma unroll
    for (int j = 0; j < 16; ++j) {
        const int e = e0 + j * 256 + t;
        int w = -1; unsigned ent = 0;
        if (e < E) {
            const int d = dst[e];
            const int s = src[e];
            w   = d >> 6;
            ent = ((unsigned)(d & (WIN - 1)) << 17) | (unsigned)s;
            atomicAdd(&cnt_s[w], 1);
        }
        wreg[j] = w; ereg[j] = ent;
    }
    __syncthreads();
    for (int w = t; w < NWIN; w += 256) {
        const int c = cnt_s[w];
        gbase_s[w] = c ? atomicAdd(&wcur[w], c) : 0;
    }
    __syncthreads();
    for (int w = t; w < NWIN; w += 256) cnt_s[w] = 0;   // reuse as local cursor
    __syncthreads();
    #pragma unroll
    for (int j = 0; j < 16; ++j) {
        const int w = wreg[j];
        if (w >= 0) {
            const int pos = gbase_s[w] + atomicAdd(&cnt_s[w], 1);
            if (pos < WCAP) bucket[(size_t)w * WCAP + pos] = ereg[j];
        }
    }
}

// ---------------------------------------------------------------------------
// wprep: Wb[n][k] = bf16 of [W1l | W1r] transposed (32768 entries), then
// W2b[k][32] = bf16 of [W2l(c<14) | 0 | W2r(c<14) | 0]   (4096 entries).
// ---------------------------------------------------------------------------
__global__ __launch_bounds__(256) void wprep_kernel(
    const float* __restrict__ W1l, const float* __restrict__ W1r,
    const float* __restrict__ W2l, const float* __restrict__ W2r,
    unsigned short* __restrict__ Wb, unsigned short* __restrict__ W2b)
{
    const int idx = blockIdx.x * 256 + threadIdx.x;
    if (idx < 2 * 128 * 128) {
        const int c   = idx >> 14;
        const int rem = idx & 16383;
        const int n   = rem >> 7;
        const int k   = rem & 127;
        const float* W = c ? W1r : W1l;
        Wb[idx] = f2bf(W[k * 128 + n]);
    } else if (idx < 2 * 128 * 128 + 128 * 32) {
        const int j = idx - 2 * 128 * 128;
        const int k = j >> 5;
        const int c = j & 31;
        float wv = 0.0f;
        if (c < 16) { if (c < C_OUT) wv = W2l[k * C_OUT + c]; }
        else        { if (c - 16 < C_OUT) wv = W2r[k * C_OUT + (c - 16)]; }
        W2b[j] = f2bf(wv);
    }
}

// ---------------------------------------------------------------------------
// pre1 (MFMA): pq = [ x@W1l | x@W1r + b1 ]  (bf16, [NN][256]).  (unchanged)
// ---------------------------------------------------------------------------
#define KS 72
__global__ __launch_bounds__(256, 2) void pre1_kernel(
    const float* __restrict__ x, const unsigned short* __restrict__ Wb,
    const float* __restrict__ b1, unsigned short* __restrict__ pq)
{
    __shared__ unsigned short lds[128 * KS + 256 * KS];
    unsigned short* A_s = lds;
    unsigned short* W_s = lds + 128 * KS;

    const int t    = threadIdx.x;
    const int m0   = blockIdx.x * 128;
    const int lane = t & 63;
    const int wave = t >> 6;
    const int lr   = lane & 15;
    const int quad = lane >> 4;
    const int nw0  = wave * 64;

    v4f acc[8][4];
    #pragma unroll
    for (int mt = 0; mt < 8; ++mt)
        #pragma unroll
        for (int nt = 0; nt < 4; ++nt)
            acc[mt][nt] = (v4f){0.f, 0.f, 0.f, 0.f};

    #pragma unroll
    for (int ph = 0; ph < 2; ++ph) {
        const int kh = ph * 64;
        if (ph) __syncthreads();

        {
            const int mi = t & 127;
            const int ko = (t >> 7) * 32;
            const int m  = m0 + mi;
            unsigned short* dp = &A_s[mi * KS + ko];
            if (m < NN) {
                const float4* sp = (const float4*)(x + (size_t)m * F + kh + ko);
                #pragma unroll
                for (int j = 0; j < 8; j += 2) {
                    const float4 f0 = sp[j], f1 = sp[j + 1];
                    uint4 o;
                    o.x = pack2(f0.x, f0.y); o.y = pack2(f0.z, f0.w);
                    o.z = pack2(f1.x, f1.y); o.w = pack2(f1.z, f1.w);
                    *(uint4*)(dp + j * 4) = o;
                }
            } else {
                #pragma unroll
                for (int j = 0; j < 4; ++j)
                    *(uint4*)(dp + j * 8) = make_uint4(0u, 0u, 0u, 0u);
            }
        }
        {
            const unsigned short* sp = Wb + (size_t)t * 128 + kh;
            unsigned short* dp = &W_s[t * KS];
            #pragma unroll
            for (int j = 0; j < 8; ++j)
                *(uint4*)(dp + j * 8) = *(const uint4*)(sp + j * 8);
        }
        __syncthreads();

        #pragma unroll
        for (int ks = 0; ks < 2; ++ks) {
            const int k0 = ks * 32 + quad * 8;
            const v8s b0 = *(const v8s*)&W_s[(nw0 +  0 + lr) * KS + k0];
            const v8s b1v= *(const v8s*)&W_s[(nw0 + 16 + lr) * KS + k0];
            const v8s b2 = *(const v8s*)&W_s[(nw0 + 32 + lr) * KS + k0];
            const v8s b3 = *(const v8s*)&W_s[(nw0 + 48 + lr) * KS + k0];
            #pragma unroll
            for (int mt = 0; mt < 8; ++mt) {
                const v8s a = *(const v8s*)&A_s[(mt * 16 + lr) * KS + k0];
                acc[mt][0] = __builtin_amdgcn_mfma_f32_16x16x32_bf16(a, b0,  acc[mt][0], 0, 0, 0);
                acc[mt][1] = __builtin_amdgcn_mfma_f32_16x16x32_bf16(a, b1v, acc[mt][1], 0, 0, 0);
                acc[mt][2] = __builtin_amdgcn_mfma_f32_16x16x32_bf16(a, b2,  acc[mt][2], 0, 0, 0);
                acc[mt][3] = __builtin_amdgcn_mfma_f32_16x16x32_bf16(a, b3,  acc[mt][3], 0, 0, 0);
            }
        }
        __syncthreads();
    }

    float bias[4];
    #pragma unroll
    for (int nt = 0; nt < 4; ++nt) {
        const int n = nw0 + nt * 16 + lr;
        bias[nt] = (n >= 128) ? b1[n - 128] : 0.0f;
    }

    unsigned short* C_s = lds;
    #pragma unroll
    for (int p = 0; p < 2; ++p) {
        if ((nw0 >> 7) == p) {
            #pragma unroll
            for (int mt = 0; mt < 8; ++mt)
                #pragma unroll
                for (int nt = 0; nt < 4; ++nt) {
                    const int n = (nw0 & 127) + nt * 16 + lr;
                    #pragma unroll
                    for (int r = 0; r < 4; ++r) {
                        const int m = mt * 16 + quad * 4 + r;
                        C_s[m * 136 + n] = f2bf(acc[mt][nt][r] + bias[nt]);
                    }
                }
        }
        __syncthreads();
        {
            const int mi = t & 127;
            const int nh = (t >> 7) * 64;
            const int m  = m0 + mi;
            if (m < NN) {
                unsigned short* dp = pq + (size_t)m * 256 + p * 128 + nh;
                const unsigned short* sp = &C_s[mi * 136 + nh];
                #pragma unroll
                for (int j = 0; j < 8; ++j)
                    *(uint4*)(dp + j * 8) = *(const uint4*)(sp + j * 8);
            }
        }
        __syncthreads();
    }
}

// ---------------------------------------------------------------------------
// agg1f: window-local CSR sort + register gather (R10 structure), with pre2
// FUSED: h rows stay in LDS (bf16), z/r computed in-block -> hb buffer and
// pre2 kernel deleted (saves 51 MB round-trip + a dispatch).
// LDS: 5.6+5.6+0.75+17.4+8 = 37.6 KB -> 4 blocks/CU (same waves as R10).
// ---------------------------------------------------------------------------
__global__ __launch_bounds__(256) void agg1f_kernel(
    const unsigned short* __restrict__ pq, const unsigned* __restrict__ bucket,
    const int* __restrict__ wcur, const unsigned short* __restrict__ W2b,
    const float* __restrict__ b2,
    unsigned short* __restrict__ z, float* __restrict__ r)
{
    __shared__ unsigned raw[WCAP];
    __shared__ unsigned list[WCAP];
    __shared__ int cnt_s[WIN], base_s[WIN], cur_s[WIN];
    __shared__ unsigned short hsm[WIN * HS];   // 17.4 KB bf16
    __shared__ unsigned short W2s[128 * 32];   // 8 KB bf16
    const int t  = threadIdx.x;
    const int wb = blockIdx.x;
    const int cntw = min(wcur[wb], WCAP);
    const unsigned* bp = bucket + (size_t)wb * WCAP;

    // stage W2 (independent of the sort)
    #pragma unroll
    for (int i = 0; i < 2; ++i) {
        const int j = i * 256 + t;
        ((uint4*)W2s)[j] = ((const uint4*)W2b)[j];
    }

    if (t < WIN) cnt_s[t] = 0;
    for (int i = t; i < cntw; i += 256) raw[i] = bp[i];
    __syncthreads();
    for (int i = t; i < cntw; i += 256) atomicAdd(&cnt_s[raw[i] >> 17], 1);
    __syncthreads();
    if (t < WIN) base_s[t] = cnt_s[t];
    __syncthreads();
    for (int off = 1; off < WIN; off <<= 1) {
        int v = 0;
        if (t < WIN && t >= off) v = base_s[t - off];
        __syncthreads();
        if (t < WIN) base_s[t] += v;
        __syncthreads();
    }
    if (t < WIN) { const int b = base_s[t] - cnt_s[t]; base_s[t] = b; cur_s[t] = b; }
    __syncthreads();
    for (int i = t; i < cntw; i += 256) {
        const unsigned e = raw[i];
        list[atomicAdd(&cur_s[e >> 17], 1)] = e & 0x1FFFFu;
    }
    __syncthreads();

    const int g    = t >> 4;      // 16 groups
    const int lane = t & 15;
    const int col  = lane * 8;
    #pragma unroll
    for (int rep = 0; rep < 4; ++rep) {
        const int nloc = rep * 16 + g;
        const int n = wb * WIN + nloc;
        if (n >= NN) continue;
        const int start = base_s[nloc];
        const int len   = cnt_s[nloc];
        float a0[8] = {0,0,0,0,0,0,0,0};
        float a1[8] = {0,0,0,0,0,0,0,0};
        float a2[8] = {0,0,0,0,0,0,0,0};
        float a3[8] = {0,0,0,0,0,0,0,0};
        int i = 0;
        for (; i + 4 <= len; i += 4) {
            const int s0 = (int)list[start + i + 0];
            const int s1 = (int)list[start + i + 1];
            const int s2 = (int)list[start + i + 2];
            const int s3 = (int)list[start + i + 3];
            const uint4 u0 = *(const uint4*)(pq + (size_t)s0 * 256 + col);
            const uint4 u1 = *(const uint4*)(pq + (size_t)s1 * 256 + col);
            const uint4 u2 = *(const uint4*)(pq + (size_t)s2 * 256 + col);
            const uint4 u3 = *(const uint4*)(pq + (size_t)s3 * 256 + col);
            float f0, f1;
            unpack2(u0.x, f0, f1); a0[0] += f0; a0[1] += f1;
            unpack2(u0.y, f0, f1); a0[2] += f0; a0[3] += f1;
            unpack2(u0.z, f0, f1); a0[4] += f0; a0[5] += f1;
            unpack2(u0.w, f0, f1); a0[6] += f0; a0[7] += f1;
            unpack2(u1.x, f0, f1); a1[0] += f0; a1[1] += f1;
            unpack2(u1.y, f0, f1); a1[2] += f0; a1[3] += f1;
            unpack2(u1.z, f0, f1); a1[4] += f0; a1[5] += f1;
            unpack2(u1.w, f0, f1); a1[6] += f0; a1[7] += f1;
            unpack2(u2.x, f0, f1); a2[0] += f0; a2[1] += f1;
            unpack2(u2.y, f0, f1); a2[2] += f0; a2[3] += f1;
            unpack2(u2.z, f0, f1); a2[4] += f0; a2[5] += f1;
            unpack2(u2.w, f0, f1); a2[6] += f0; a2[7] += f1;
            unpack2(u3.x, f0, f1); a3[0] += f0; a3[1] += f1;
            unpack2(u3.y, f0, f1); a3[2] += f0; a3[3] += f1;
            unpack2(u3.z, f0, f1); a3[4] += f0; a3[5] += f1;
            unpack2(u3.w, f0, f1); a3[6] += f0; a3[7] += f1;
        }
        for (; i < len; ++i) {
            const int s = (int)list[start + i];
            const uint4 u = *(const uint4*)(pq + (size_t)s * 256 + col);
            float f0, f1;
            unpack2(u.x, f0, f1); a0[0] += f0; a0[1] += f1;
            unpack2(u.y, f0, f1); a0[2] += f0; a0[3] += f1;
            unpack2(u.z, f0, f1); a0[4] += f0; a0[5] += f1;
            unpack2(u.w, f0, f1); a0[6] += f0; a0[7] += f1;
        }
        const float inv = 1.0f / (float)max(len, 1);
        const uint4 uq = *(const uint4*)(pq + (size_t)n * 256 + 128 + col);
        float q[8];
        unpack2(uq.x, q[0], q[1]); unpack2(uq.y, q[2], q[3]);
        unpack2(uq.z, q[4], q[5]); unpack2(uq.w, q[6], q[7]);
        float hv[8];
        #pragma unroll
        for (int j = 0; j < 8; ++j)
            hv[j] = fmaxf((a0[j] + a1[j] + a2[j] + a3[j]) * inv + q[j], 0.0f);
        uint4 o;
        o.x = pack2(hv[0], hv[1]);
        o.y = pack2(hv[2], hv[3]);
        o.z = pack2(hv[4], hv[5]);
        o.w = pack2(hv[6], hv[7]);
        *(uint4*)&hsm[nloc * HS + col] = o;
    }
    __syncthreads();

    // fused pre2: z|r = h @ W2s for this window's 64 nodes.
    // thread -> (nloc = t&63, cg = t>>6); cg 0,1 -> z cols, cg 2,3 -> r cols.
    {
        const int nloc = t & 63;
        const int cg   = t >> 6;
        const int n    = wb * WIN + nloc;
        if (n < NN) {
            float acc8[8] = {0,0,0,0,0,0,0,0};
            for (int k = 0; k < 128; k += 8) {
                const uint4 hu = *(const uint4*)&hsm[nloc * HS + k];
                float hv[8];
                unpack2(hu.x, hv[0], hv[1]); unpack2(hu.y, hv[2], hv[3]);
                unpack2(hu.z, hv[4], hv[5]); unpack2(hu.w, hv[6], hv[7]);
                #pragma unroll
                for (int kk = 0; kk < 8; ++kk) {
                    const uint4 wu = *(const uint4*)&W2s[(k + kk) * 32 + cg * 8];
                    float wv[8];
                    unpack2(wu.x, wv[0], wv[1]); unpack2(wu.y, wv[2], wv[3]);
                    unpack2(wu.z, wv[4], wv[5]); unpack2(wu.w, wv[6], wv[7]);
                    #pragma unroll
                    for (int j = 0; j < 8; ++j)
                        acc8[j] += hv[kk] * wv[j];
                }
            }
            if (cg < 2) {            // z (bf16), cols cg*8..cg*8+8 (>=14 are 0)
                uint4 o;
                o.x = pack2(acc8[0], acc8[1]);
                o.y = pack2(acc8[2], acc8[3]);
                o.z = pack2(acc8[4], acc8[5]);
                o.w = pack2(acc8[6], acc8[7]);
                *(uint4*)(z + (size_t)n * ZP + cg * 8) = o;
            } else {                 // r (fp32) + bias
                const int rc = (cg - 2) * 8;
                float4 o0, o1;
                o0.x = acc8[0] + ((rc + 0 < C_OUT) ? b2[rc + 0] : 0.0f);
                o0.y = acc8[1] + ((rc + 1 < C_OUT) ? b2[rc + 1] : 0.0f);
                o0.z = acc8[2] + ((rc + 2 < C_OUT) ? b2[rc + 2] : 0.0f);
                o0.w = acc8[3] + ((rc + 3 < C_OUT) ? b2[rc + 3] : 0.0f);
                o1.x = acc8[4] + ((rc + 4 < C_OUT) ? b2[rc + 4] : 0.0f);
                o1.y = acc8[5] + ((rc + 5 < C_OUT) ? b2[rc + 5] : 0.0f);
                o1.z = acc8[6] + ((rc + 6 < C_OUT) ? b2[rc + 6] : 0.0f);
                o1.w = acc8[7] + ((rc + 7 < C_OUT) ? b2[rc + 7] : 0.0f);
                *(float4*)(r + (size_t)n * ZP + rc)     = o0;
                *(float4*)(r + (size_t)n * ZP + rc + 4) = o1;
            }
        }
    }
}

// ---------------------------------------------------------------------------
// agg2s: window-local CSR sort, gather z (32B rows), fused dual log_softmax.
// (unchanged from R10)
// ---------------------------------------------------------------------------
__global__ __launch_bounds__(256) void agg2s_kernel(
    const unsigned short* __restrict__ z, const float* __restrict__ r,
    const unsigned* __restrict__ bucket, const int* __restrict__ wcur,
    const int* __restrict__ sf_ptr, float* __restrict__ out)
{
    __shared__ unsigned raw[WCAP];
    __shared__ unsigned list[WCAP];
    __shared__ int cnt_s[WIN], base_s[WIN], cur_s[WIN];
    __shared__ float sm[WIN][ZP + 1];
    const int t  = threadIdx.x;
    const int wb = blockIdx.x;
    const int cntw = min(wcur[wb], WCAP);
    const unsigned* bp = bucket + (size_t)wb * WCAP;

    if (t < WIN) cnt_s[t] = 0;
    for (int i = t; i < cntw; i += 256) raw[i] = bp[i];
    __syncthreads();
    for (int i = t; i < cntw; i += 256) atomicAdd(&cnt_s[raw[i] >> 17], 1);
    __syncthreads();
    if (t < WIN) base_s[t] = cnt_s[t];
    __syncthreads();
    for (int off = 1; off < WIN; off <<= 1) {
        int v = 0;
        if (t < WIN && t >= off) v = base_s[t - off];
        __syncthreads();
        if (t < WIN) base_s[t] += v;
        __syncthreads();
    }
    if (t < WIN) { const int b = base_s[t] - cnt_s[t]; base_s[t] = b; cur_s[t] = b; }
    __syncthreads();
    for (int i = t; i < cntw; i += 256) {
        const unsigned e = raw[i];
        list[atomicAdd(&cur_s[e >> 17], 1)] = e & 0x1FFFFu;
    }
    __syncthreads();

    const int g  = t >> 2;      // node slot 0..63
    const int j4 = (t & 3) * 4;
    const int n  = wb * WIN + g;
    if (n < NN) {
        const int start = base_s[g];
        const int len   = cnt_s[g];
        float4 a0 = make_float4(0.f, 0.f, 0.f, 0.f);
        float4 a1 = a0, a2 = a0, a3 = a0;
        int i = 0;
        for (; i + 4 <= len; i += 4) {
            const int s0 = (int)list[start + i + 0];
            const int s1 = (int)list[start + i + 1];
            const int s2 = (int)list[start + i + 2];
            const int s3 = (int)list[start + i + 3];
            const uint2 u0 = *(const uint2*)(z + (size_t)s0 * ZP + j4);
            const uint2 u1 = *(const uint2*)(z + (size_t)s1 * ZP + j4);
            const uint2 u2 = *(const uint2*)(z + (size_t)s2 * ZP + j4);
            const uint2 u3 = *(const uint2*)(z + (size_t)s3 * ZP + j4);
            float f0, f1, f2, f3;
            unpack2(u0.x, f0, f1); unpack2(u0.y, f2, f3);
            a0.x += f0; a0.y += f1; a0.z += f2; a0.w += f3;
            unpack2(u1.x, f0, f1); unpack2(u1.y, f2, f3);
            a1.x += f0; a1.y += f1; a1.z += f2; a1.w += f3;
            unpack2(u2.x, f0, f1); unpack2(u2.y, f2, f3);
            a2.x += f0; a2.y += f1; a2.z += f2; a2.w += f3;
            unpack2(u3.x, f0, f1); unpack2(u3.y, f2, f3);
            a3.x += f0; a3.y += f1; a3.z += f2; a3.w += f3;
        }
        for (; i < len; ++i) {
            const int s = (int)list[start + i];
            const uint2 u = *(const uint2*)(z + (size_t)s * ZP + j4);
            float f0, f1, f2, f3;
            unpack2(u.x, f0, f1); unpack2(u.y, f2, f3);
            a0.x += f0; a0.y += f1; a0.z += f2; a0.w += f3;
        }
        const float inv = 1.0f / (float)max(len, 1);
        const float4 rv = *(const float4*)(r + (size_t)n * ZP + j4);
        sm[g][j4 + 0] = (a0.x + a1.x + a2.x + a3.x) * inv + rv.x;
        sm[g][j4 + 1] = (a0.y + a1.y + a2.y + a3.y) * inv + rv.y;
        sm[g][j4 + 2] = (a0.z + a1.z + a2.z + a3.z) * inv + rv.z;
        sm[g][j4 + 3] = (a0.w + a1.w + a2.w + a3.w) * inv + rv.w;
    }
    __syncthreads();

    if (t < WIN) {
        const int n2 = wb * WIN + t;
        if (n2 < NN) {
            const int sf = *sf_ptr;
            const float* row = sm[t];
            float m = -1e30f;
            for (int c = 0; c < sf; ++c) m = fmaxf(m, row[c]);
            float s = 0.0f;
            for (int c = 0; c < sf; ++c) s += expf(row[c] - m);
            float ls = m + logf(s);
            for (int c = 0; c < sf; ++c)
                out[(long long)n2 * sf + c] = row[c] - ls;
            m = -1e30f;
            for (int c = sf; c < C_OUT; ++c) m = fmaxf(m, row[c]);
            s = 0.0f;
            for (int c = sf; c < C_OUT; ++c) s += expf(row[c] - m);
            ls = m + logf(s);
            const int pt = C_OUT - sf;
            for (int c = sf; c < C_OUT; ++c)
                out[(long long)NN * sf + (long long)n2 * pt + (c - sf)] = row[c] - ls;
        }
    }
}

// ---------------------------------------------------------------------------
extern "C" void kernel_launch(void* const* d_in, const int* in_sizes, int n_in,
                              void* d_out, int out_size, void* d_ws, size_t ws_size,
                              hipStream_t stream)
{
    const float* x   = (const float*)d_in[0];
    const int*   ei  = (const int*)d_in[1];
    const int*   sfp = (const int*)d_in[2];
    const float* W1l = (const float*)d_in[3];
    const float* W1r = (const float*)d_in[4];
    const float* b1  = (const float*)d_in[5];
    const float* W2l = (const float*)d_in[6];
    const float* W2r = (const float*)d_in[7];
    const float* b2  = (const float*)d_in[8];
    float*       out = (float*)d_out;

    const int E = in_sizes[1] / 2;
    const int* src = ei;
    const int* dst = ei + E;

    // ws layout (words). hb deleted; z/r are separate small buffers (no alias
    // with pq since agg1f reads pq while writing z/r).
    int*      wcur   = (int*)d_ws;                             // 2048
    unsigned* bucket = (unsigned*)(wcur + 2048);               // NWIN*WCAP
    unsigned short* Wb  = (unsigned short*)(bucket + (size_t)NWIN * WCAP); // 32768
    unsigned short* W2b = Wb + 2 * 128 * 128;                  // 4096
    unsigned short* pq  = W2b + 128 * 32;                      // NN*256 bf16
    unsigned short* z   = pq + (size_t)NN * 256;               // NN*16 bf16
    float*          r   = (float*)(z + (size_t)NN * ZP);       // NN*16 fp32

    hipMemsetAsync(wcur, 0, 2048 * sizeof(int), stream);

    // edge binning into 64-node windows
    bin_kernel<<<(E + EBATCH - 1) / EBATCH, 256, 0, stream>>>(src, dst, bucket, wcur, E);

    // weight prep (W1 transposed bf16 + W2 padded bf16)
    wprep_kernel<<<(2 * 128 * 128 + 128 * 32 + 255) / 256, 256, 0, stream>>>(
        W1l, W1r, W2l, W2r, Wb, W2b);

    // layer-1 GEMM (MFMA)
    pre1_kernel<<<(NN + 127) / 128, 256, 0, stream>>>(x, Wb, b1, pq);

    // layer-1 aggregation + fused layer-2 GEMM -> z, r
    agg1f_kernel<<<NWIN, 256, 0, stream>>>(pq, bucket, wcur, W2b, b2, z, r);

    // layer-2 aggregation + softmax
    agg2s_kernel<<<NWIN, 256, 0, stream>>>(z, r, bucket, wcur, sfp, out);
}